// Round 13
// baseline (517.400 us; speedup 1.0000x reference)
//
#include <hip/hip_runtime.h>

#define HW 4096

typedef _Float16 f16;
typedef _Float16 f16x4 __attribute__((ext_vector_type(4)));
typedef _Float16 f16x8 __attribute__((ext_vector_type(8)));
typedef float    f32x4 __attribute__((ext_vector_type(4)));
typedef unsigned long long u64;

// ---------------------------------------------------------------------------
// fused prep: L1 weight transpose, MFMA weight repacks (w1..w3), w4 q-frag
// repack, and border-only zeroing of the padded f32 activation buffers.
// ---------------------------------------------------------------------------
__device__ inline void wrepack_one(const float* __restrict__ w,
                                   f16* __restrict__ wh, f16* __restrict__ wl,
                                   int cin, int idx)
{
  int j    = idx & 7;
  int lane = (idx >> 3) & 63;
  int mt   = (idx >> 9) & 3;
  int t    = idx >> 11;
  int tap  = t % 9;
  int t2   = t / 9;
  int chunks = cin >> 5;
  int chk  = t2 % chunks;
  int cg   = t2 / chunks;
  int co = cg * 64 + mt * 16 + (lane & 15);
  int k  = chk * 32 + 8 * (lane >> 4) + j;
  float v = w[((size_t)co * cin + k) * 9 + tap];
  f16 h = (f16)v;
  wh[idx] = h;
  wl[idx] = (f16)((v - (float)h) * 4096.0f);
}

__device__ inline void bzero_one(float* __restrict__ o, int C, int idx)
{
  int ch = idx % C;
  int rest = idx / C;
  int bp = rest % 260, bb = rest / 260;
  int r, c;
  if (bp < 66)       { r = 0;  c = bp; }
  else if (bp < 132) { r = 65; c = bp - 66; }
  else if (bp < 196) { c = 0;  r = bp - 132 + 1; }
  else               { c = 65; r = bp - 196 + 1; }
  o[(((size_t)bb * 66 + r) * 66 + c) * C + ch] = 0.f;
}

__global__ __launch_bounds__(256) void prep_kernel(
    const float* __restrict__ w0, float* __restrict__ wt0,
    const float* __restrict__ w1, f16* __restrict__ wh1, f16* __restrict__ wl1,
    const float* __restrict__ w2, f16* __restrict__ wh2, f16* __restrict__ wl2,
    const float* __restrict__ w3, f16* __restrict__ wh3, f16* __restrict__ wl3,
    const float* __restrict__ w4, f16* __restrict__ w4h, f16* __restrict__ w4l,
    float* __restrict__ a32f, float* __restrict__ b64f,
    float* __restrict__ a128f, int G)
{
  int idx = blockIdx.x * 256 + threadIdx.x;
  if (idx < 864) {                       // L1 wtrans: [(c*9+tap)][co]
    int co = idx % 32, rest = idx / 32;
    wt0[rest * 32 + co] = w0[co * 27 + rest];
    return;
  }
  idx -= 864;
  if (idx < 18432)  { wrepack_one(w1, wh1, wl1, 32, idx);  return; }
  idx -= 18432;
  if (idx < 73728)  { wrepack_one(w2, wh2, wl2, 64, idx);  return; }
  idx -= 73728;
  if (idx < 294912) { wrepack_one(w3, wh3, wl3, 128, idx); return; }
  idx -= 294912;
  if (idx < 4096) {                      // w4 q-frag repack
    int j = idx & 7, lane = (idx >> 3) & 63, cp = idx >> 9;
    int tap = lane & 15;
    int k = 8 * (lane >> 4) + j;
    int co = cp * 32 + k;
    float v = (tap < 9) ? w4[co * 9 + tap] : 0.f;
    f16 h = (f16)v;
    w4h[idx] = h;
    w4l[idx] = (f16)((v - (float)h) * 4096.0f);
    return;
  }
  idx -= 4096;
  int n32 = G * 260 * 32;
  if (idx < n32) { bzero_one(a32f, 32, idx); return; }
  idx -= n32;
  int n64 = G * 260 * 64;
  if (idx < n64) { bzero_one(b64f, 64, idx); return; }
  idx -= n64;
  int n128 = G * 260 * 128;
  if (idx < n128) { bzero_one(a128f, 128, idx); return; }
}

// ---------------------------------------------------------------------------
// L1: direct f32 3->32 conv + BN + ReLU -> padded NHWC f32 [66][66][32]
// ---------------------------------------------------------------------------
__global__ __launch_bounds__(128) void conv_l1_kernel(
    const float* __restrict__ mapd, const float* __restrict__ startm,
    const float* __restrict__ goalm,
    float* __restrict__ o32,         // [G][66][66][32]
    const float* __restrict__ wt,    // [(c*9+tap)][32]
    const float* __restrict__ bconv,
    const float* __restrict__ gamma, const float* __restrict__ beta,
    int b0)
{
  __shared__ float sIn[3][18][20];
  __shared__ float sW[3][9][32];
  const int tile = blockIdx.x;
  const int b    = blockIdx.z;
  const int gb   = b0 + b;
  const int y0 = (tile >> 2) << 4, x0 = (tile & 3) << 4;
  const int tid = threadIdx.x;
  const int cg = tid >> 6;
  const int pg = tid & 63;
  const int py = pg >> 2, px0 = (pg & 3) << 2;

  float acc[4][16];
  #pragma unroll
  for (int i = 0; i < 4; ++i)
    #pragma unroll
    for (int j = 0; j < 16; ++j) acc[i][j] = 0.f;

  for (int idx = tid; idx < 3 * 324; idx += 128) {
    int c = idx / 324, rem = idx - c * 324;
    int iy = rem / 18, ix = rem - iy * 18;
    int gy = y0 - 1 + iy, gx = x0 - 1 + ix;
    float v = 0.f;
    if ((unsigned)gy < 64u && (unsigned)gx < 64u) {
      const float* sp = (c == 0) ? mapd : ((c == 1) ? startm : goalm);
      v = sp[(gb << 12) + (gy << 6) + gx];
    }
    sIn[c][iy][ix] = v;
  }
  for (int idx = tid; idx < 3 * 9 * 32; idx += 128) {
    int co = idx % 32;
    int rest = idx / 32;
    sW[rest / 9][rest % 9][co] = wt[(size_t)rest * 32 + co];
  }
  __syncthreads();
  for (int c = 0; c < 3; ++c) {
    #pragma unroll
    for (int dy = 0; dy < 3; ++dy) {
      const float* rowp = &sIn[c][py + dy][px0];
      float4 ra = *(const float4*)rowp;
      float4 rb = *(const float4*)(rowp + 4);
      float r[6] = {ra.x, ra.y, ra.z, ra.w, rb.x, rb.y};
      #pragma unroll
      for (int dx = 0; dx < 3; ++dx) {
        const float4* wp = (const float4*)&sW[c][dy * 3 + dx][cg * 16];
        float4 w0 = wp[0], w1 = wp[1], w2 = wp[2], w3 = wp[3];
        float wv[16] = {w0.x, w0.y, w0.z, w0.w, w1.x, w1.y, w1.z, w1.w,
                        w2.x, w2.y, w2.z, w2.w, w3.x, w3.y, w3.z, w3.w};
        #pragma unroll
        for (int i = 0; i < 4; ++i)
          #pragma unroll
          for (int j = 0; j < 16; ++j)
            acc[i][j] = fmaf(r[dx + i], wv[j], acc[i][j]);
      }
    }
  }
  #pragma unroll
  for (int j = 0; j < 16; ++j) {
    int co = cg * 16 + j;
    float sc = gamma[co] / sqrtf(1.0f + 1e-5f);
    float bb = bconv[co], sh = beta[co];
    #pragma unroll
    for (int i = 0; i < 4; ++i) {
      float v = (acc[i][j] + bb) * sc + sh;
      v = fmaxf(v, 0.f);
      o32[(((size_t)b * 66 + (y0 + py + 1)) * 66 + (x0 + px0 + i + 1)) * 32 + co] = v;
    }
  }
}

// ---------------------------------------------------------------------------
// MFMA implicit-GEMM 3x3 conv, f16x3 split (exact to ~2^-22 rel/product).
// R13: register-prefetch software pipeline (T14) -- chunk k+1's activation
// float4s are loaded into registers while chunk k's MFMAs run, removing the
// per-chunk global-load latency + vmcnt drain from the critical path.
// Numerics bit-identical to R12.
// ---------------------------------------------------------------------------
template<int CIN, int COUT, bool QOUT>
__global__ __launch_bounds__(512, 4) void mfmaconv_kernel(
    const float* __restrict__ x,
    float* __restrict__ onhwc,
    float* __restrict__ qout,                 // [G][8][9][4096] when QOUT
    const f16* __restrict__ wh, const f16* __restrict__ wl,
    const f16* __restrict__ w4h, const f16* __restrict__ w4l,
    const float* __restrict__ bconv,
    const float* __restrict__ gamma, const float* __restrict__ beta)
{
  constexpr int CHUNKS = CIN / 32;
  __shared__ __align__(16) char smem[396 * 32 * 2 * 2];   // 50688 B
  f16* sH = (f16*)smem;
  f16* sL = sH + 396 * 32;
  float (*sT)[36] = (float(*)[36])smem;                    // reused

  const int tid  = threadIdx.x;
  const int w    = tid >> 6, lane = tid & 63;
  const int l15  = lane & 15, lk = lane >> 4;
  const int rw   = w & 3, ch2 = w >> 2;
  const int tile = blockIdx.x;           // 0..15 (4 rows each)
  const int y0g  = tile << 2;
  const int cog  = blockIdx.y;
  const int cog0 = cog << 6;
  const int b    = blockIdx.z;

  f32x4 acc1[4][2], acc2[4][2];
  #pragma unroll
  for (int mt = 0; mt < 4; ++mt)
    #pragma unroll
    for (int n2 = 0; n2 < 2; ++n2) { acc1[mt][n2] = (f32x4)0.f; acc2[mt][n2] = (f32x4)0.f; }

  // precomputed per-thread staging coordinates (static 7-deep, rule #20)
  float4 stg[7];
  int srow[7], scol[7];
  #pragma unroll
  for (int it = 0; it < 7; ++it) {
    int q = it * 512 + tid;
    int px = q >> 3;
    srow[it] = px / 66;
    scol[it] = px - srow[it] * 66;
  }

  // prologue: issue chunk-0 loads
  #pragma unroll
  for (int it = 0; it < 7; ++it) {
    int q = it * 512 + tid;
    if (q < 3168) {
      int c4 = q & 7;
      stg[it] = *(const float4*)&x[(((size_t)b * 66 + y0g + srow[it]) * 66 + scol[it]) * CIN
                                   + 0 * 32 + c4 * 4];
    }
  }

  for (int chk = 0; chk < CHUNKS; ++chk) {
    __syncthreads();   // prior compute done reading LDS
    // split the prefetched registers and write to LDS
    #pragma unroll
    for (int it = 0; it < 7; ++it) {
      int q = it * 512 + tid;
      if (q < 3168) {
        int c4 = q & 7;
        int px = q >> 3;
        float vv[4] = {stg[it].x, stg[it].y, stg[it].z, stg[it].w};
        f16x4 hv, lv;
        #pragma unroll
        for (int j = 0; j < 4; ++j) {
          f16 h = (f16)vv[j];
          hv[j] = h;
          lv[j] = (f16)((vv[j] - (float)h) * 4096.0f);
        }
        *(f16x4*)&sH[px * 32 + c4 * 4] = hv;
        *(f16x4*)&sL[px * 32 + c4 * 4] = lv;
      }
    }
    __syncthreads();
    // issue chunk k+1 loads (latency hides under the MFMA phase below)
    if (chk + 1 < CHUNKS) {
      #pragma unroll
      for (int it = 0; it < 7; ++it) {
        int q = it * 512 + tid;
        if (q < 3168) {
          int c4 = q & 7;
          stg[it] = *(const float4*)&x[(((size_t)b * 66 + y0g + srow[it]) * 66 + scol[it]) * CIN
                                       + (chk + 1) * 32 + c4 * 4];
        }
      }
    }
    #pragma unroll
    for (int tap = 0; tap < 9; ++tap) {
      const int dy = tap / 3, dx = tap - dy * 3;
      f16x8 Bh[2], Bl[2];
      #pragma unroll
      for (int n2 = 0; n2 < 2; ++n2) {
        int hp = (rw + dy) * 66 + (ch2 * 32 + n2 * 16 + l15 + dx);
        Bh[n2] = *(const f16x8*)&sH[hp * 32 + 8 * lk];
        Bl[n2] = *(const f16x8*)&sL[hp * 32 + 8 * lk];
      }
      #pragma unroll
      for (int mt = 0; mt < 4; ++mt) {
        size_t aoff = ((((size_t)(cog * CHUNKS + chk) * 9 + tap) * 4 + mt) * 64 + lane) * 8;
        f16x8 Ah = *(const f16x8*)&wh[aoff];
        f16x8 Al = *(const f16x8*)&wl[aoff];
        #pragma unroll
        for (int n2 = 0; n2 < 2; ++n2) {
          acc1[mt][n2] = __builtin_amdgcn_mfma_f32_16x16x32_f16(Ah, Bh[n2], acc1[mt][n2], 0, 0, 0);
          acc2[mt][n2] = __builtin_amdgcn_mfma_f32_16x16x32_f16(Ah, Bl[n2], acc2[mt][n2], 0, 0, 0);
          acc2[mt][n2] = __builtin_amdgcn_mfma_f32_16x16x32_f16(Al, Bh[n2], acc2[mt][n2], 0, 0, 0);
        }
      }
    }
  }

  // epilogue: two 32-cout passes via LDS transpose
  #pragma unroll
  for (int p = 0; p < 2; ++p) {
    __syncthreads();
    #pragma unroll
    for (int m1 = 0; m1 < 2; ++m1) {
      const int mt = 2 * p + m1;
      #pragma unroll
      for (int n2 = 0; n2 < 2; ++n2)
        #pragma unroll
        for (int i = 0; i < 4; ++i) {
          int co = cog0 + p * 32 + m1 * 16 + 4 * lk + i;
          float v = acc1[mt][n2][i] + acc2[mt][n2][i] * (1.0f / 4096.0f);
          float sc = gamma[co] / sqrtf(1.0f + 1e-5f);
          v = (v + bconv[co]) * sc + beta[co];
          v = fmaxf(v, 0.f);
          sT[rw * 64 + ch2 * 32 + n2 * 16 + l15][m1 * 16 + 4 * lk + i] = v;
        }
    }
    __syncthreads();
    if constexpr (QOUT) {
      const int cp = cog * 2 + p;
      f16x8 A_h = *(const f16x8*)&w4h[(cp * 64 + lane) * 8];
      f16x8 A_l = *(const f16x8*)&w4l[(cp * 64 + lane) * 8];
      #pragma unroll
      for (int nt2 = 0; nt2 < 2; ++nt2) {
        int nt = w * 2 + nt2;
        const float* bp = &sT[nt * 16 + l15][8 * lk];
        float4 v0 = *(const float4*)bp;
        float4 v1 = *(const float4*)(bp + 4);
        float bvv[8] = {v0.x, v0.y, v0.z, v0.w, v1.x, v1.y, v1.z, v1.w};
        f16x8 Bh, Bl;
        #pragma unroll
        for (int j = 0; j < 8; ++j) {
          f16 h = (f16)bvv[j];
          Bh[j] = h;
          Bl[j] = (f16)((bvv[j] - (float)h) * 4096.0f);
        }
        f32x4 q1 = (f32x4)0.f, q2 = (f32x4)0.f;
        q1 = __builtin_amdgcn_mfma_f32_16x16x32_f16(A_h, Bh, q1, 0, 0, 0);
        q2 = __builtin_amdgcn_mfma_f32_16x16x32_f16(A_h, Bl, q2, 0, 0, 0);
        q2 = __builtin_amdgcn_mfma_f32_16x16x32_f16(A_l, Bh, q2, 0, 0, 0);
        #pragma unroll
        for (int i = 0; i < 4; ++i) {
          int tap = 4 * lk + i;
          if (tap < 9)
            qout[(((size_t)b * 8 + cp) * 9 + tap) * HW + tile * 256 + nt * 16 + l15]
                = q1[i] + q2[i] * (1.0f / 4096.0f);
        }
      }
    } else {
      int px = tid >> 1, half = tid & 1;
      int row = px >> 6, col = px & 63;
      size_t base = (((size_t)b * 66 + y0g + row + 1) * 66 + col + 1) * COUT
                    + cog0 + p * 32 + half * 16;
      #pragma unroll
      for (int jj = 0; jj < 4; ++jj) {
        float4 o;
        o.x = sT[px][half * 16 + jj * 4 + 0];
        o.y = sT[px][half * 16 + jj * 4 + 1];
        o.z = sT[px][half * 16 + jj * 4 + 2];
        o.w = sT[px][half * 16 + jj * 4 + 3];
        *(float4*)&onhwc[base + jj * 4] = o;
      }
    }
  }
}

// ---------------------------------------------------------------------------
// heads finish (unchanged)
// ---------------------------------------------------------------------------
__global__ __launch_bounds__(256) void heads2_kernel(
    const float* __restrict__ q4,       // [G][8][9][4096]
    const float* __restrict__ b4, const float* __restrict__ gm4,
    const float* __restrict__ bt4,
    const float* __restrict__ cw, const float* __restrict__ cb,
    const float* __restrict__ gw, const float* __restrict__ gb,
    const float* __restrict__ ow, const float* __restrict__ ob,
    float* __restrict__ costout,
    float* __restrict__ geoout, float* __restrict__ obsout,
    int b0)
{
  const int bl = blockIdx.y;
  const int px = blockIdx.x * 256 + threadIdx.x;
  const int y = px >> 6, x = px & 63;
  float s = 0.f;
  for (int cp = 0; cp < 8; ++cp) {
    const float* qb = &q4[((size_t)bl * 8 + cp) * 9 * HW];
    #pragma unroll
    for (int tap = 0; tap < 9; ++tap) {
      int yy = y + tap / 3 - 1, xx = x + tap % 3 - 1;
      if ((unsigned)yy < 64u && (unsigned)xx < 64u)
        s += qb[tap * HW + (yy << 6) + xx];
    }
  }
  float sc = gm4[0] / sqrtf(1.0f + 1e-5f);
  float f  = (s + b4[0]) * sc + bt4[0];
  float cv = 1.f / (1.f + expf(-(f * cw[0] + cb[0])));
  float gv = fmaxf(f * gw[0] + gb[0], 0.f);
  float ov = fmaxf(f * ow[0] + ob[0], 0.f);
  int gbi = b0 + bl;
  costout[gbi * HW + px] = cv;
  geoout[gbi * HW + px]  = gv;
  obsout[gbi * HW + px]  = ov;
}

// ---------------------------------------------------------------------------
// A* pass 1 (unchanged from R12 -- proven; u64 keys + exp factoring)
// ---------------------------------------------------------------------------
__device__ inline u64 pkey(float fe, int idx) {
  return ((u64)__float_as_uint(fe) << 32) | (unsigned)(~idx);
}

__global__ __launch_bounds__(64) void astar_pass1_kernel(
    const float* __restrict__ costm,
    const float* __restrict__ startm,
    const float* __restrict__ goalm,
    const float* __restrict__ mapd,
    unsigned short* __restrict__ Jmeta,
    unsigned short* __restrict__ Jcells)
{
  __shared__ float4 cell[HW];   // g, flag, Eh(=exp(-h/16)), cost
  __shared__ float2 pk[HW];     // fe, gc(=g+cost)
  const int b = blockIdx.x, lane = threadIdx.x;

  int gi = 0x7fffffff;
  for (int i = lane; i < HW; i += 64)
    if (goalm[b * HW + i] > 0.5f) gi = min(gi, i);
  #pragma unroll
  for (int m = 32; m; m >>= 1) gi = min(gi, __shfl_xor(gi, m));
  const int goal_idx = gi;
  const float gyf = (float)(goal_idx >> 6), gxf = (float)(goal_idx & 63);

  for (int i = lane; i < HW; i += 64) {
    float c_ = costm[b * HW + i];
    float iy = (float)(i >> 6), ix = (float)(i & 63);
    float d0 = fabsf(iy - gyf), d1 = fabsf(ix - gxf);
    float cheb = (d0 + d1) - fminf(d0, d1);
    float euc  = sqrtf(d0 * d0 + d1 * d1);
    float h = (cheb + 0.001f * euc) + c_;
    float Eh = expf(-((0.5f * h) * 0.125f));   // exp(-h/16)
    bool st = startm[b * HW + i] > 0.5f;
    float flg = st ? 1.f : ((mapd[b * HW + i] > 0.5f) ? 0.f : 2.f);
    cell[i] = make_float4(0.f, flg, Eh, c_);
    pk[i] = make_float2(st ? Eh : 0.f, c_);
  }
  __syncthreads();

  u64 gmk = 0ull; float ggc = 0.f;
  {
    int base = lane << 6;
    for (int k = 0; k < 64; ++k) {
      int ci = base + ((k + lane) & 63);
      float2 p = pk[ci];
      u64 kk = pkey(p.x, ci);
      if (kk > gmk) { gmk = kk; ggc = p.y; }
    }
  }

  u64 K = gmk; float gc = ggc;
  #pragma unroll
  for (int m = 32; m; m >>= 1) {
    u64 ko = __shfl_xor(K, m);
    float co = __shfl_xor(gc, m);
    if (ko > K) { K = ko; gc = co; }
  }

  int t = 0;
  for (; t < 512; ++t) {
    const int ind = (int)(~(unsigned)K) & (HW - 1);
    const float g2 = gc;
    const bool unsolved = (ind != goal_idx);
    const int r = ind >> 6, cx = ind & 63;
    const float eg = expf(-g2 * 0.0625f);    // wave-uniform, off-chain

    const int rb = (r << 6) + lane;
    float2 rp = pk[rb];

    int pcell = -1; float pval = 0.f, pgc = 0.f;
    if (lane < 8) {
      int kk = (lane >= 4) ? lane + 1 : lane;
      int ny = r + (kk / 3) - 1, nx = cx + (kk % 3) - 1;
      if ((unsigned)ny < 64u && (unsigned)nx < 64u) {
        int n = (ny << 6) + nx;
        float4 cd = cell[n];
        bool trig = (cd.y == 1.f) ? (cd.x > g2) : (cd.y == 0.f);
        if (trig) {
          float fv = eg * cd.z;
          *(float2*)&cell[n] = make_float2(g2, 1.f);
          pk[n] = make_float2(fv, g2 + cd.w);
          pcell = n; pval = fv; pgc = g2 + cd.w;
        }
      }
      Jcells[((size_t)b * 512 + t) * 8 + lane] =
          (unsigned short)(pcell >= 0 ? pcell : 0xFFFF);
    } else if (lane == 8) {
      if (unsolved) {
        cell[ind].y = 2.f;
        pk[ind].x  = 0.f;
      }
      Jmeta[b * 512 + t] = (unsigned short)(ind | (unsolved ? 0 : 0x8000));
    }

    u64 kB = (unsolved && lane == cx) ? 0ull : pkey(rp.x, rb);
    float bgc = rp.y;

    const bool fixpoint = (!unsolved) && !__any(pcell >= 0);
    if (fixpoint) { ++t; break; }

    #pragma unroll
    for (int k = 0; k < 8; ++k) {
      int   pc = __shfl(pcell, k);
      float pv = __shfl(pval, k);
      float pg = __shfl(pgc, k);
      if (pc >= 0) {
        u64 kk = pkey(pv, pc);
        if ((pc >> 6) == r && (pc & 63) == lane) {
          if (kk > kB) { kB = kk; bgc = pg; }
        }
        if ((pc >> 6) == lane) {
          if (kk > gmk) { gmk = kk; ggc = pg; }
        }
      }
    }

    u64 kC; float cgc;
    if (unsolved && lane == r) { kC = kB; cgc = bgc; }
    else if (gmk > kB)         { kC = gmk; cgc = ggc; }
    else                       { kC = kB;  cgc = bgc; }

    #pragma unroll
    for (int m = 32; m; m >>= 1) {
      u64   ko  = __shfl_xor(kC, m);
      float co  = __shfl_xor(cgc, m);
      u64   kbo = __shfl_xor(kB, m);
      float bgo = __shfl_xor(bgc, m);
      if (ko  > kC) { kC = ko;  cgc = co;  }
      if (kbo > kB) { kB = kbo; bgc = bgo; }
    }
    if (unsolved && lane == r) { gmk = kB; ggc = bgc; }
    K = kC; gc = cgc;
  }

  {
    unsigned short jm = (unsigned short)(goal_idx | 0x8000);
    uint4* jc4 = (uint4*)Jcells;
    for (int tt = t + lane; tt < 512; tt += 64) {
      Jmeta[b * 512 + tt] = jm;
      jc4[(size_t)b * 512 + tt] =
          make_uint4(0xFFFFFFFFu, 0xFFFFFFFFu, 0xFFFFFFFFu, 0xFFFFFFFFu);
    }
  }
}

// ---------------------------------------------------------------------------
// A* pass 2 (unchanged)
// ---------------------------------------------------------------------------
__global__ __launch_bounds__(64) void astar_pass2_kernel(
    const unsigned short* __restrict__ Jmeta,
    const unsigned short* __restrict__ Jcells,
    const float* __restrict__ goalm,
    float* __restrict__ out_hist, float* __restrict__ out_path)
{
  __shared__ unsigned short par[HW];
  __shared__ unsigned short jm[64];
  __shared__ unsigned short jc[64][8];
  const int b = blockIdx.x, lane = threadIdx.x;

  for (int i = lane; i < HW; i += 64) {
    out_hist[b * HW + i] = 0.f;
    out_path[b * HW + i] = 0.f;
  }
  int localmin = 512;
  for (int t = lane; t < 512; t += 64) {
    bool all16 = true;
    for (int bb = 0; bb < 16; ++bb)
      all16 = all16 && ((Jmeta[bb * 512 + t] & 0x8000u) != 0);
    if (all16) localmin = min(localmin, t);
  }
  #pragma unroll
  for (int m = 32; m; m >>= 1) localmin = min(localmin, __shfl_xor(localmin, m));
  const int t_last = (localmin < 512) ? localmin : 511;

  int gi = 0x7fffffff;
  for (int i = lane; i < HW; i += 64)
    if (goalm[b * HW + i] > 0.5f) gi = min(gi, i);
  #pragma unroll
  for (int m = 32; m; m >>= 1) gi = min(gi, __shfl_xor(gi, m));

  for (int i = lane; i < HW; i += 64) par[i] = (unsigned short)gi;
  __syncthreads();

  for (int t0 = 0; t0 <= t_last; t0 += 64) {
    if (t0 + lane < 512) {
      jm[lane] = Jmeta[b * 512 + t0 + lane];
      const unsigned short* src = &Jcells[((size_t)b * 512 + t0 + lane) * 8];
      #pragma unroll
      for (int k = 0; k < 8; ++k) jc[lane][k] = src[k];
    }
    __syncthreads();
    int te = min(t_last - t0, 63);
    for (int tt = 0; tt <= te; ++tt) {
      int ind = jm[tt] & 0x0FFF;
      if (lane < 8) {
        unsigned short c = jc[tt][lane];
        if (c != 0xFFFFu) par[c] = (unsigned short)ind;
      } else if (lane == 8) {
        out_hist[b * HW + ind] = 1.0f;
      }
    }
    __syncthreads();
  }
  if (lane == 0) {
    out_path[b * HW + gi] = 1.0f;
    int loc = par[gi];
    for (int i = 0; i < t_last; ++i) {
      out_path[b * HW + loc] = 1.0f;
      loc = par[loc];
    }
  }
}

// ---------------------------------------------------------------------------
extern "C" void kernel_launch(void* const* d_in, const int* in_sizes, int n_in,
                              void* d_out, int out_size, void* d_ws, size_t ws_size,
                              hipStream_t stream)
{
  (void)in_sizes; (void)n_in; (void)out_size;
  const float* mapd   = (const float*)d_in[0];
  const float* startm = (const float*)d_in[1];
  const float* goalm  = (const float*)d_in[2];
  const float* w0 = (const float*)d_in[3];
  const float* b0 = (const float*)d_in[4];
  const float* gm0= (const float*)d_in[5];
  const float* bt0= (const float*)d_in[6];
  const float* w1 = (const float*)d_in[7];
  const float* b1 = (const float*)d_in[8];
  const float* gm1= (const float*)d_in[9];
  const float* bt1= (const float*)d_in[10];
  const float* w2 = (const float*)d_in[11];
  const float* b2 = (const float*)d_in[12];
  const float* gm2= (const float*)d_in[13];
  const float* bt2= (const float*)d_in[14];
  const float* w3 = (const float*)d_in[15];
  const float* b3 = (const float*)d_in[16];
  const float* gm3= (const float*)d_in[17];
  const float* bt3= (const float*)d_in[18];
  const float* w4 = (const float*)d_in[19];
  const float* b4 = (const float*)d_in[20];
  const float* gm4= (const float*)d_in[21];
  const float* bt4= (const float*)d_in[22];
  const float* cw = (const float*)d_in[23];
  const float* cb = (const float*)d_in[24];
  const float* gw = (const float*)d_in[25];
  const float* gb = (const float*)d_in[26];
  const float* owp= (const float*)d_in[27];
  const float* obp= (const float*)d_in[28];
  float* out = (float*)d_out;

  char* wsb = (char*)d_ws;
  size_t off = 0;
  auto alloc = [&](size_t bytes) {
    void* p = wsb + off;
    off = (off + bytes + 255) & ~(size_t)255;
    return p;
  };
  float* wt0 = (float*)alloc(864 * 4);
  f16* wh1 = (f16*)alloc(64  * 9 * 32  * 2);
  f16* wl1 = (f16*)alloc(64  * 9 * 32  * 2);
  f16* wh2 = (f16*)alloc(128 * 9 * 64  * 2);
  f16* wl2 = (f16*)alloc(128 * 9 * 64  * 2);
  f16* wh3 = (f16*)alloc(256 * 9 * 128 * 2);
  f16* wl3 = (f16*)alloc(256 * 9 * 128 * 2);
  f16* w4h = (f16*)alloc(4096 * 2);
  f16* w4l = (f16*)alloc(4096 * 2);
  float* costb = (float*)alloc(16 * HW * 4);
  unsigned short* Jmeta  = (unsigned short*)alloc(16 * 512 * 2);
  unsigned short* Jcells = (unsigned short*)alloc(16 * 512 * 8 * 2);
  size_t fixed = off;

  const size_t A32  = 66 * 66 * 32  * 4;
  const size_t B64  = 66 * 66 * 64  * 4;
  const size_t A128 = 66 * 66 * 128 * 4;
  const size_t Q4   = 8 * 9 * HW * 4;
  const size_t perG = A32 + B64 + A128 + Q4 + 4 * 256;

  int G = 16;
  while (G > 1 && fixed + (size_t)G * perG > ws_size) G >>= 1;

  float* a32f  = (float*)alloc(G * A32);
  float* b64f  = (float*)alloc(G * B64);
  float* a128f = (float*)alloc(G * A128);
  float* q4    = (float*)alloc(G * Q4);

  int prep_total = 864 + 18432 + 73728 + 294912 + 4096 + G * 260 * (32 + 64 + 128);
  prep_kernel<<<(prep_total + 255) / 256, 256, 0, stream>>>(
      w0, wt0, w1, wh1, wl1, w2, wh2, wl2, w3, wh3, wl3, w4, w4h, w4l,
      a32f, b64f, a128f, G);

  for (int g0 = 0; g0 < 16; g0 += G) {
    conv_l1_kernel<<<dim3(16, 1, G), 128, 0, stream>>>(
        mapd, startm, goalm, a32f, wt0, b0, gm0, bt0, g0);
    mfmaconv_kernel<32, 64, false><<<dim3(16, 1, G), 512, 0, stream>>>(
        a32f, b64f, nullptr, wh1, wl1, nullptr, nullptr, b1, gm1, bt1);
    mfmaconv_kernel<64, 128, false><<<dim3(16, 2, G), 512, 0, stream>>>(
        b64f, a128f, nullptr, wh2, wl2, nullptr, nullptr, b2, gm2, bt2);
    mfmaconv_kernel<128, 256, true><<<dim3(16, 4, G), 512, 0, stream>>>(
        a128f, nullptr, q4, wh3, wl3, w4h, w4l, b3, gm3, bt3);
    heads2_kernel<<<dim3(16, G), 256, 0, stream>>>(
        q4, b4, gm4, bt4, cw, cb, gw, gb, owp, obp,
        costb, out + 2 * 16 * HW, out + 3 * 16 * HW, g0);
  }

  astar_pass1_kernel<<<16, 64, 0, stream>>>(costb, startm, goalm, mapd, Jmeta, Jcells);
  astar_pass2_kernel<<<16, 64, 0, stream>>>(Jmeta, Jcells, goalm, out, out + 16 * HW);
}

// Round 14
// 391.352 us; speedup vs baseline: 1.3221x; 1.3221x over previous
//
#include <hip/hip_runtime.h>

#define HW 4096

typedef _Float16 f16;
typedef _Float16 f16x4 __attribute__((ext_vector_type(4)));
typedef _Float16 f16x8 __attribute__((ext_vector_type(8)));
typedef float    f32x4 __attribute__((ext_vector_type(4)));
typedef unsigned long long u64;

// ---------------------------------------------------------------------------
// fused prep: L1 weight transpose, MFMA weight repacks (w1..w3), w4 q-frag
// repack, and border-only zeroing of the padded f32 activation buffers.
// ---------------------------------------------------------------------------
__device__ inline void wrepack_one(const float* __restrict__ w,
                                   f16* __restrict__ wh, f16* __restrict__ wl,
                                   int cin, int idx)
{
  int j    = idx & 7;
  int lane = (idx >> 3) & 63;
  int mt   = (idx >> 9) & 3;
  int t    = idx >> 11;
  int tap  = t % 9;
  int t2   = t / 9;
  int chunks = cin >> 5;
  int chk  = t2 % chunks;
  int cg   = t2 / chunks;
  int co = cg * 64 + mt * 16 + (lane & 15);
  int k  = chk * 32 + 8 * (lane >> 4) + j;
  float v = w[((size_t)co * cin + k) * 9 + tap];
  f16 h = (f16)v;
  wh[idx] = h;
  wl[idx] = (f16)((v - (float)h) * 4096.0f);
}

__device__ inline void bzero_one(float* __restrict__ o, int C, int idx)
{
  int ch = idx % C;
  int rest = idx / C;
  int bp = rest % 260, bb = rest / 260;
  int r, c;
  if (bp < 66)       { r = 0;  c = bp; }
  else if (bp < 132) { r = 65; c = bp - 66; }
  else if (bp < 196) { c = 0;  r = bp - 132 + 1; }
  else               { c = 65; r = bp - 196 + 1; }
  o[(((size_t)bb * 66 + r) * 66 + c) * C + ch] = 0.f;
}

__global__ __launch_bounds__(256) void prep_kernel(
    const float* __restrict__ w0, float* __restrict__ wt0,
    const float* __restrict__ w1, f16* __restrict__ wh1, f16* __restrict__ wl1,
    const float* __restrict__ w2, f16* __restrict__ wh2, f16* __restrict__ wl2,
    const float* __restrict__ w3, f16* __restrict__ wh3, f16* __restrict__ wl3,
    const float* __restrict__ w4, f16* __restrict__ w4h, f16* __restrict__ w4l,
    float* __restrict__ a32f, float* __restrict__ b64f,
    float* __restrict__ a128f, int G)
{
  int idx = blockIdx.x * 256 + threadIdx.x;
  if (idx < 864) {                       // L1 wtrans: [(c*9+tap)][co]
    int co = idx % 32, rest = idx / 32;
    wt0[rest * 32 + co] = w0[co * 27 + rest];
    return;
  }
  idx -= 864;
  if (idx < 18432)  { wrepack_one(w1, wh1, wl1, 32, idx);  return; }
  idx -= 18432;
  if (idx < 73728)  { wrepack_one(w2, wh2, wl2, 64, idx);  return; }
  idx -= 73728;
  if (idx < 294912) { wrepack_one(w3, wh3, wl3, 128, idx); return; }
  idx -= 294912;
  if (idx < 4096) {                      // w4 q-frag repack
    int j = idx & 7, lane = (idx >> 3) & 63, cp = idx >> 9;
    int tap = lane & 15;
    int k = 8 * (lane >> 4) + j;
    int co = cp * 32 + k;
    float v = (tap < 9) ? w4[co * 9 + tap] : 0.f;
    f16 h = (f16)v;
    w4h[idx] = h;
    w4l[idx] = (f16)((v - (float)h) * 4096.0f);
    return;
  }
  idx -= 4096;
  int n32 = G * 260 * 32;
  if (idx < n32) { bzero_one(a32f, 32, idx); return; }
  idx -= n32;
  int n64 = G * 260 * 64;
  if (idx < n64) { bzero_one(b64f, 64, idx); return; }
  idx -= n64;
  int n128 = G * 260 * 128;
  if (idx < n128) { bzero_one(a128f, 128, idx); return; }
}

// ---------------------------------------------------------------------------
// L1: direct f32 3->32 conv + BN + ReLU -> padded NHWC f32 [66][66][32]
// ---------------------------------------------------------------------------
__global__ __launch_bounds__(128) void conv_l1_kernel(
    const float* __restrict__ mapd, const float* __restrict__ startm,
    const float* __restrict__ goalm,
    float* __restrict__ o32,         // [G][66][66][32]
    const float* __restrict__ wt,    // [(c*9+tap)][32]
    const float* __restrict__ bconv,
    const float* __restrict__ gamma, const float* __restrict__ beta,
    int b0)
{
  __shared__ float sIn[3][18][20];
  __shared__ float sW[3][9][32];
  const int tile = blockIdx.x;
  const int b    = blockIdx.z;
  const int gb   = b0 + b;
  const int y0 = (tile >> 2) << 4, x0 = (tile & 3) << 4;
  const int tid = threadIdx.x;
  const int cg = tid >> 6;
  const int pg = tid & 63;
  const int py = pg >> 2, px0 = (pg & 3) << 2;

  float acc[4][16];
  #pragma unroll
  for (int i = 0; i < 4; ++i)
    #pragma unroll
    for (int j = 0; j < 16; ++j) acc[i][j] = 0.f;

  for (int idx = tid; idx < 3 * 324; idx += 128) {
    int c = idx / 324, rem = idx - c * 324;
    int iy = rem / 18, ix = rem - iy * 18;
    int gy = y0 - 1 + iy, gx = x0 - 1 + ix;
    float v = 0.f;
    if ((unsigned)gy < 64u && (unsigned)gx < 64u) {
      const float* sp = (c == 0) ? mapd : ((c == 1) ? startm : goalm);
      v = sp[(gb << 12) + (gy << 6) + gx];
    }
    sIn[c][iy][ix] = v;
  }
  for (int idx = tid; idx < 3 * 9 * 32; idx += 128) {
    int co = idx % 32;
    int rest = idx / 32;
    sW[rest / 9][rest % 9][co] = wt[(size_t)rest * 32 + co];
  }
  __syncthreads();
  for (int c = 0; c < 3; ++c) {
    #pragma unroll
    for (int dy = 0; dy < 3; ++dy) {
      const float* rowp = &sIn[c][py + dy][px0];
      float4 ra = *(const float4*)rowp;
      float4 rb = *(const float4*)(rowp + 4);
      float r[6] = {ra.x, ra.y, ra.z, ra.w, rb.x, rb.y};
      #pragma unroll
      for (int dx = 0; dx < 3; ++dx) {
        const float4* wp = (const float4*)&sW[c][dy * 3 + dx][cg * 16];
        float4 w0 = wp[0], w1 = wp[1], w2 = wp[2], w3 = wp[3];
        float wv[16] = {w0.x, w0.y, w0.z, w0.w, w1.x, w1.y, w1.z, w1.w,
                        w2.x, w2.y, w2.z, w2.w, w3.x, w3.y, w3.z, w3.w};
        #pragma unroll
        for (int i = 0; i < 4; ++i)
          #pragma unroll
          for (int j = 0; j < 16; ++j)
            acc[i][j] = fmaf(r[dx + i], wv[j], acc[i][j]);
      }
    }
  }
  #pragma unroll
  for (int j = 0; j < 16; ++j) {
    int co = cg * 16 + j;
    float sc = gamma[co] / sqrtf(1.0f + 1e-5f);
    float bb = bconv[co], sh = beta[co];
    #pragma unroll
    for (int i = 0; i < 4; ++i) {
      float v = (acc[i][j] + bb) * sc + sh;
      v = fmaxf(v, 0.f);
      o32[(((size_t)b * 66 + (y0 + py + 1)) * 66 + (x0 + px0 + i + 1)) * 32 + co] = v;
    }
  }
}

// ---------------------------------------------------------------------------
// MFMA implicit-GEMM 3x3 conv, f16x3 split (exact to ~2^-22 rel/product).
// R12 structure restored exactly: simple staging loop, no register prefetch
// (R13's prefetch spilled to scratch: VGPR stayed 64, FETCH/WRITE blew up).
// ---------------------------------------------------------------------------
template<int CIN, int COUT, bool QOUT>
__global__ __launch_bounds__(512, 4) void mfmaconv_kernel(
    const float* __restrict__ x,
    float* __restrict__ onhwc,
    float* __restrict__ qout,                 // [G][8][9][4096] when QOUT
    const f16* __restrict__ wh, const f16* __restrict__ wl,
    const f16* __restrict__ w4h, const f16* __restrict__ w4l,
    const float* __restrict__ bconv,
    const float* __restrict__ gamma, const float* __restrict__ beta)
{
  constexpr int CHUNKS = CIN / 32;
  __shared__ __align__(16) char smem[396 * 32 * 2 * 2];   // 50688 B
  f16* sH = (f16*)smem;
  f16* sL = sH + 396 * 32;
  float (*sT)[36] = (float(*)[36])smem;                    // reused

  const int tid  = threadIdx.x;
  const int w    = tid >> 6, lane = tid & 63;
  const int l15  = lane & 15, lk = lane >> 4;
  const int rw   = w & 3, ch2 = w >> 2;
  const int tile = blockIdx.x;           // 0..15 (4 rows each)
  const int y0g  = tile << 2;
  const int cog  = blockIdx.y;
  const int cog0 = cog << 6;
  const int b    = blockIdx.z;

  f32x4 acc1[4][2], acc2[4][2];
  #pragma unroll
  for (int mt = 0; mt < 4; ++mt)
    #pragma unroll
    for (int n2 = 0; n2 < 2; ++n2) { acc1[mt][n2] = (f32x4)0.f; acc2[mt][n2] = (f32x4)0.f; }

  for (int chk = 0; chk < CHUNKS; ++chk) {
    __syncthreads();
    for (int idx = tid; idx < 3168; idx += 512) {
      int px = idx >> 3, c4 = idx & 7;
      int r = px / 66, c = px - r * 66;
      float4 v = *(const float4*)&x[(((size_t)b * 66 + y0g + r) * 66 + c) * CIN
                                    + chk * 32 + c4 * 4];
      float vv[4] = {v.x, v.y, v.z, v.w};
      f16x4 hv, lv;
      #pragma unroll
      for (int j = 0; j < 4; ++j) {
        f16 h = (f16)vv[j];
        hv[j] = h;
        lv[j] = (f16)((vv[j] - (float)h) * 4096.0f);
      }
      *(f16x4*)&sH[px * 32 + c4 * 4] = hv;
      *(f16x4*)&sL[px * 32 + c4 * 4] = lv;
    }
    __syncthreads();
    #pragma unroll
    for (int tap = 0; tap < 9; ++tap) {
      const int dy = tap / 3, dx = tap - dy * 3;
      f16x8 Bh[2], Bl[2];
      #pragma unroll
      for (int n2 = 0; n2 < 2; ++n2) {
        int hp = (rw + dy) * 66 + (ch2 * 32 + n2 * 16 + l15 + dx);
        Bh[n2] = *(const f16x8*)&sH[hp * 32 + 8 * lk];
        Bl[n2] = *(const f16x8*)&sL[hp * 32 + 8 * lk];
      }
      #pragma unroll
      for (int mt = 0; mt < 4; ++mt) {
        size_t aoff = ((((size_t)(cog * CHUNKS + chk) * 9 + tap) * 4 + mt) * 64 + lane) * 8;
        f16x8 Ah = *(const f16x8*)&wh[aoff];
        f16x8 Al = *(const f16x8*)&wl[aoff];
        #pragma unroll
        for (int n2 = 0; n2 < 2; ++n2) {
          acc1[mt][n2] = __builtin_amdgcn_mfma_f32_16x16x32_f16(Ah, Bh[n2], acc1[mt][n2], 0, 0, 0);
          acc2[mt][n2] = __builtin_amdgcn_mfma_f32_16x16x32_f16(Ah, Bl[n2], acc2[mt][n2], 0, 0, 0);
          acc2[mt][n2] = __builtin_amdgcn_mfma_f32_16x16x32_f16(Al, Bh[n2], acc2[mt][n2], 0, 0, 0);
        }
      }
    }
  }

  // epilogue: two 32-cout passes via LDS transpose
  #pragma unroll
  for (int p = 0; p < 2; ++p) {
    __syncthreads();
    #pragma unroll
    for (int m1 = 0; m1 < 2; ++m1) {
      const int mt = 2 * p + m1;
      #pragma unroll
      for (int n2 = 0; n2 < 2; ++n2)
        #pragma unroll
        for (int i = 0; i < 4; ++i) {
          int co = cog0 + p * 32 + m1 * 16 + 4 * lk + i;
          float v = acc1[mt][n2][i] + acc2[mt][n2][i] * (1.0f / 4096.0f);
          float sc = gamma[co] / sqrtf(1.0f + 1e-5f);
          v = (v + bconv[co]) * sc + beta[co];
          v = fmaxf(v, 0.f);
          sT[rw * 64 + ch2 * 32 + n2 * 16 + l15][m1 * 16 + 4 * lk + i] = v;
        }
    }
    __syncthreads();
    if constexpr (QOUT) {
      const int cp = cog * 2 + p;
      f16x8 A_h = *(const f16x8*)&w4h[(cp * 64 + lane) * 8];
      f16x8 A_l = *(const f16x8*)&w4l[(cp * 64 + lane) * 8];
      #pragma unroll
      for (int nt2 = 0; nt2 < 2; ++nt2) {
        int nt = w * 2 + nt2;
        const float* bp = &sT[nt * 16 + l15][8 * lk];
        float4 v0 = *(const float4*)bp;
        float4 v1 = *(const float4*)(bp + 4);
        float bvv[8] = {v0.x, v0.y, v0.z, v0.w, v1.x, v1.y, v1.z, v1.w};
        f16x8 Bh, Bl;
        #pragma unroll
        for (int j = 0; j < 8; ++j) {
          f16 h = (f16)bvv[j];
          Bh[j] = h;
          Bl[j] = (f16)((bvv[j] - (float)h) * 4096.0f);
        }
        f32x4 q1 = (f32x4)0.f, q2 = (f32x4)0.f;
        q1 = __builtin_amdgcn_mfma_f32_16x16x32_f16(A_h, Bh, q1, 0, 0, 0);
        q2 = __builtin_amdgcn_mfma_f32_16x16x32_f16(A_h, Bl, q2, 0, 0, 0);
        q2 = __builtin_amdgcn_mfma_f32_16x16x32_f16(A_l, Bh, q2, 0, 0, 0);
        #pragma unroll
        for (int i = 0; i < 4; ++i) {
          int tap = 4 * lk + i;
          if (tap < 9)
            qout[(((size_t)b * 8 + cp) * 9 + tap) * HW + tile * 256 + nt * 16 + l15]
                = q1[i] + q2[i] * (1.0f / 4096.0f);
        }
      }
    } else {
      int px = tid >> 1, half = tid & 1;
      int row = px >> 6, col = px & 63;
      size_t base = (((size_t)b * 66 + y0g + row + 1) * 66 + col + 1) * COUT
                    + cog0 + p * 32 + half * 16;
      #pragma unroll
      for (int jj = 0; jj < 4; ++jj) {
        float4 o;
        o.x = sT[px][half * 16 + jj * 4 + 0];
        o.y = sT[px][half * 16 + jj * 4 + 1];
        o.z = sT[px][half * 16 + jj * 4 + 2];
        o.w = sT[px][half * 16 + jj * 4 + 3];
        *(float4*)&onhwc[base + jj * 4] = o;
      }
    }
  }
}

// ---------------------------------------------------------------------------
// heads finish (unchanged)
// ---------------------------------------------------------------------------
__global__ __launch_bounds__(256) void heads2_kernel(
    const float* __restrict__ q4,       // [G][8][9][4096]
    const float* __restrict__ b4, const float* __restrict__ gm4,
    const float* __restrict__ bt4,
    const float* __restrict__ cw, const float* __restrict__ cb,
    const float* __restrict__ gw, const float* __restrict__ gb,
    const float* __restrict__ ow, const float* __restrict__ ob,
    float* __restrict__ costout,
    float* __restrict__ geoout, float* __restrict__ obsout,
    int b0)
{
  const int bl = blockIdx.y;
  const int px = blockIdx.x * 256 + threadIdx.x;
  const int y = px >> 6, x = px & 63;
  float s = 0.f;
  for (int cp = 0; cp < 8; ++cp) {
    const float* qb = &q4[((size_t)bl * 8 + cp) * 9 * HW];
    #pragma unroll
    for (int tap = 0; tap < 9; ++tap) {
      int yy = y + tap / 3 - 1, xx = x + tap % 3 - 1;
      if ((unsigned)yy < 64u && (unsigned)xx < 64u)
        s += qb[tap * HW + (yy << 6) + xx];
    }
  }
  float sc = gm4[0] / sqrtf(1.0f + 1e-5f);
  float f  = (s + b4[0]) * sc + bt4[0];
  float cv = 1.f / (1.f + expf(-(f * cw[0] + cb[0])));
  float gv = fmaxf(f * gw[0] + gb[0], 0.f);
  float ov = fmaxf(f * ow[0] + ob[0], 0.f);
  int gbi = b0 + bl;
  costout[gbi * HW + px] = cv;
  geoout[gbi * HW + px]  = gv;
  obsout[gbi * HW + px]  = ov;
}

// ---------------------------------------------------------------------------
// A* pass 1 (R12 -- u64 packed keys + exp factoring)
// ---------------------------------------------------------------------------
__device__ inline u64 pkey(float fe, int idx) {
  return ((u64)__float_as_uint(fe) << 32) | (unsigned)(~idx);
}

__global__ __launch_bounds__(64) void astar_pass1_kernel(
    const float* __restrict__ costm,
    const float* __restrict__ startm,
    const float* __restrict__ goalm,
    const float* __restrict__ mapd,
    unsigned short* __restrict__ Jmeta,
    unsigned short* __restrict__ Jcells)
{
  __shared__ float4 cell[HW];   // g, flag, Eh(=exp(-h/16)), cost
  __shared__ float2 pk[HW];     // fe, gc(=g+cost)
  const int b = blockIdx.x, lane = threadIdx.x;

  int gi = 0x7fffffff;
  for (int i = lane; i < HW; i += 64)
    if (goalm[b * HW + i] > 0.5f) gi = min(gi, i);
  #pragma unroll
  for (int m = 32; m; m >>= 1) gi = min(gi, __shfl_xor(gi, m));
  const int goal_idx = gi;
  const float gyf = (float)(goal_idx >> 6), gxf = (float)(goal_idx & 63);

  for (int i = lane; i < HW; i += 64) {
    float c_ = costm[b * HW + i];
    float iy = (float)(i >> 6), ix = (float)(i & 63);
    float d0 = fabsf(iy - gyf), d1 = fabsf(ix - gxf);
    float cheb = (d0 + d1) - fminf(d0, d1);
    float euc  = sqrtf(d0 * d0 + d1 * d1);
    float h = (cheb + 0.001f * euc) + c_;
    float Eh = expf(-((0.5f * h) * 0.125f));   // exp(-h/16)
    bool st = startm[b * HW + i] > 0.5f;
    float flg = st ? 1.f : ((mapd[b * HW + i] > 0.5f) ? 0.f : 2.f);
    cell[i] = make_float4(0.f, flg, Eh, c_);
    pk[i] = make_float2(st ? Eh : 0.f, c_);
  }
  __syncthreads();

  u64 gmk = 0ull; float ggc = 0.f;
  {
    int base = lane << 6;
    for (int k = 0; k < 64; ++k) {
      int ci = base + ((k + lane) & 63);
      float2 p = pk[ci];
      u64 kk = pkey(p.x, ci);
      if (kk > gmk) { gmk = kk; ggc = p.y; }
    }
  }

  u64 K = gmk; float gc = ggc;
  #pragma unroll
  for (int m = 32; m; m >>= 1) {
    u64 ko = __shfl_xor(K, m);
    float co = __shfl_xor(gc, m);
    if (ko > K) { K = ko; gc = co; }
  }

  int t = 0;
  for (; t < 512; ++t) {
    const int ind = (int)(~(unsigned)K) & (HW - 1);
    const float g2 = gc;
    const bool unsolved = (ind != goal_idx);
    const int r = ind >> 6, cx = ind & 63;
    const float eg = expf(-g2 * 0.0625f);    // wave-uniform, off-chain

    const int rb = (r << 6) + lane;
    float2 rp = pk[rb];

    int pcell = -1; float pval = 0.f, pgc = 0.f;
    if (lane < 8) {
      int kk = (lane >= 4) ? lane + 1 : lane;
      int ny = r + (kk / 3) - 1, nx = cx + (kk % 3) - 1;
      if ((unsigned)ny < 64u && (unsigned)nx < 64u) {
        int n = (ny << 6) + nx;
        float4 cd = cell[n];
        bool trig = (cd.y == 1.f) ? (cd.x > g2) : (cd.y == 0.f);
        if (trig) {
          float fv = eg * cd.z;
          *(float2*)&cell[n] = make_float2(g2, 1.f);
          pk[n] = make_float2(fv, g2 + cd.w);
          pcell = n; pval = fv; pgc = g2 + cd.w;
        }
      }
      Jcells[((size_t)b * 512 + t) * 8 + lane] =
          (unsigned short)(pcell >= 0 ? pcell : 0xFFFF);
    } else if (lane == 8) {
      if (unsolved) {
        cell[ind].y = 2.f;
        pk[ind].x  = 0.f;
      }
      Jmeta[b * 512 + t] = (unsigned short)(ind | (unsolved ? 0 : 0x8000));
    }

    u64 kB = (unsolved && lane == cx) ? 0ull : pkey(rp.x, rb);
    float bgc = rp.y;

    const bool fixpoint = (!unsolved) && !__any(pcell >= 0);
    if (fixpoint) { ++t; break; }

    #pragma unroll
    for (int k = 0; k < 8; ++k) {
      int   pc = __shfl(pcell, k);
      float pv = __shfl(pval, k);
      float pg = __shfl(pgc, k);
      if (pc >= 0) {
        u64 kk = pkey(pv, pc);
        if ((pc >> 6) == r && (pc & 63) == lane) {
          if (kk > kB) { kB = kk; bgc = pg; }
        }
        if ((pc >> 6) == lane) {
          if (kk > gmk) { gmk = kk; ggc = pg; }
        }
      }
    }

    u64 kC; float cgc;
    if (unsolved && lane == r) { kC = kB; cgc = bgc; }
    else if (gmk > kB)         { kC = gmk; cgc = ggc; }
    else                       { kC = kB;  cgc = bgc; }

    #pragma unroll
    for (int m = 32; m; m >>= 1) {
      u64   ko  = __shfl_xor(kC, m);
      float co  = __shfl_xor(cgc, m);
      u64   kbo = __shfl_xor(kB, m);
      float bgo = __shfl_xor(bgc, m);
      if (ko  > kC) { kC = ko;  cgc = co;  }
      if (kbo > kB) { kB = kbo; bgc = bgo; }
    }
    if (unsolved && lane == r) { gmk = kB; ggc = bgc; }
    K = kC; gc = cgc;
  }

  {
    unsigned short jm = (unsigned short)(goal_idx | 0x8000);
    uint4* jc4 = (uint4*)Jcells;
    for (int tt = t + lane; tt < 512; tt += 64) {
      Jmeta[b * 512 + tt] = jm;
      jc4[(size_t)b * 512 + tt] =
          make_uint4(0xFFFFFFFFu, 0xFFFFFFFFu, 0xFFFFFFFFu, 0xFFFFFFFFu);
    }
  }
}

// ---------------------------------------------------------------------------
// A* pass 2 (unchanged)
// ---------------------------------------------------------------------------
__global__ __launch_bounds__(64) void astar_pass2_kernel(
    const unsigned short* __restrict__ Jmeta,
    const unsigned short* __restrict__ Jcells,
    const float* __restrict__ goalm,
    float* __restrict__ out_hist, float* __restrict__ out_path)
{
  __shared__ unsigned short par[HW];
  __shared__ unsigned short jm[64];
  __shared__ unsigned short jc[64][8];
  const int b = blockIdx.x, lane = threadIdx.x;

  for (int i = lane; i < HW; i += 64) {
    out_hist[b * HW + i] = 0.f;
    out_path[b * HW + i] = 0.f;
  }
  int localmin = 512;
  for (int t = lane; t < 512; t += 64) {
    bool all16 = true;
    for (int bb = 0; bb < 16; ++bb)
      all16 = all16 && ((Jmeta[bb * 512 + t] & 0x8000u) != 0);
    if (all16) localmin = min(localmin, t);
  }
  #pragma unroll
  for (int m = 32; m; m >>= 1) localmin = min(localmin, __shfl_xor(localmin, m));
  const int t_last = (localmin < 512) ? localmin : 511;

  int gi = 0x7fffffff;
  for (int i = lane; i < HW; i += 64)
    if (goalm[b * HW + i] > 0.5f) gi = min(gi, i);
  #pragma unroll
  for (int m = 32; m; m >>= 1) gi = min(gi, __shfl_xor(gi, m));

  for (int i = lane; i < HW; i += 64) par[i] = (unsigned short)gi;
  __syncthreads();

  for (int t0 = 0; t0 <= t_last; t0 += 64) {
    if (t0 + lane < 512) {
      jm[lane] = Jmeta[b * 512 + t0 + lane];
      const unsigned short* src = &Jcells[((size_t)b * 512 + t0 + lane) * 8];
      #pragma unroll
      for (int k = 0; k < 8; ++k) jc[lane][k] = src[k];
    }
    __syncthreads();
    int te = min(t_last - t0, 63);
    for (int tt = 0; tt <= te; ++tt) {
      int ind = jm[tt] & 0x0FFF;
      if (lane < 8) {
        unsigned short c = jc[tt][lane];
        if (c != 0xFFFFu) par[c] = (unsigned short)ind;
      } else if (lane == 8) {
        out_hist[b * HW + ind] = 1.0f;
      }
    }
    __syncthreads();
  }
  if (lane == 0) {
    out_path[b * HW + gi] = 1.0f;
    int loc = par[gi];
    for (int i = 0; i < t_last; ++i) {
      out_path[b * HW + loc] = 1.0f;
      loc = par[loc];
    }
  }
}

// ---------------------------------------------------------------------------
extern "C" void kernel_launch(void* const* d_in, const int* in_sizes, int n_in,
                              void* d_out, int out_size, void* d_ws, size_t ws_size,
                              hipStream_t stream)
{
  (void)in_sizes; (void)n_in; (void)out_size;
  const float* mapd   = (const float*)d_in[0];
  const float* startm = (const float*)d_in[1];
  const float* goalm  = (const float*)d_in[2];
  const float* w0 = (const float*)d_in[3];
  const float* b0 = (const float*)d_in[4];
  const float* gm0= (const float*)d_in[5];
  const float* bt0= (const float*)d_in[6];
  const float* w1 = (const float*)d_in[7];
  const float* b1 = (const float*)d_in[8];
  const float* gm1= (const float*)d_in[9];
  const float* bt1= (const float*)d_in[10];
  const float* w2 = (const float*)d_in[11];
  const float* b2 = (const float*)d_in[12];
  const float* gm2= (const float*)d_in[13];
  const float* bt2= (const float*)d_in[14];
  const float* w3 = (const float*)d_in[15];
  const float* b3 = (const float*)d_in[16];
  const float* gm3= (const float*)d_in[17];
  const float* bt3= (const float*)d_in[18];
  const float* w4 = (const float*)d_in[19];
  const float* b4 = (const float*)d_in[20];
  const float* gm4= (const float*)d_in[21];
  const float* bt4= (const float*)d_in[22];
  const float* cw = (const float*)d_in[23];
  const float* cb = (const float*)d_in[24];
  const float* gw = (const float*)d_in[25];
  const float* gb = (const float*)d_in[26];
  const float* owp= (const float*)d_in[27];
  const float* obp= (const float*)d_in[28];
  float* out = (float*)d_out;

  char* wsb = (char*)d_ws;
  size_t off = 0;
  auto alloc = [&](size_t bytes) {
    void* p = wsb + off;
    off = (off + bytes + 255) & ~(size_t)255;
    return p;
  };
  float* wt0 = (float*)alloc(864 * 4);
  f16* wh1 = (f16*)alloc(64  * 9 * 32  * 2);
  f16* wl1 = (f16*)alloc(64  * 9 * 32  * 2);
  f16* wh2 = (f16*)alloc(128 * 9 * 64  * 2);
  f16* wl2 = (f16*)alloc(128 * 9 * 64  * 2);
  f16* wh3 = (f16*)alloc(256 * 9 * 128 * 2);
  f16* wl3 = (f16*)alloc(256 * 9 * 128 * 2);
  f16* w4h = (f16*)alloc(4096 * 2);
  f16* w4l = (f16*)alloc(4096 * 2);
  float* costb = (float*)alloc(16 * HW * 4);
  unsigned short* Jmeta  = (unsigned short*)alloc(16 * 512 * 2);
  unsigned short* Jcells = (unsigned short*)alloc(16 * 512 * 8 * 2);
  size_t fixed = off;

  const size_t A32  = 66 * 66 * 32  * 4;
  const size_t B64  = 66 * 66 * 64  * 4;
  const size_t A128 = 66 * 66 * 128 * 4;
  const size_t Q4   = 8 * 9 * HW * 4;
  const size_t perG = A32 + B64 + A128 + Q4 + 4 * 256;

  int G = 16;
  while (G > 1 && fixed + (size_t)G * perG > ws_size) G >>= 1;

  float* a32f  = (float*)alloc(G * A32);
  float* b64f  = (float*)alloc(G * B64);
  float* a128f = (float*)alloc(G * A128);
  float* q4    = (float*)alloc(G * Q4);

  int prep_total = 864 + 18432 + 73728 + 294912 + 4096 + G * 260 * (32 + 64 + 128);
  prep_kernel<<<(prep_total + 255) / 256, 256, 0, stream>>>(
      w0, wt0, w1, wh1, wl1, w2, wh2, wl2, w3, wh3, wl3, w4, w4h, w4l,
      a32f, b64f, a128f, G);

  for (int g0 = 0; g0 < 16; g0 += G) {
    conv_l1_kernel<<<dim3(16, 1, G), 128, 0, stream>>>(
        mapd, startm, goalm, a32f, wt0, b0, gm0, bt0, g0);
    mfmaconv_kernel<32, 64, false><<<dim3(16, 1, G), 512, 0, stream>>>(
        a32f, b64f, nullptr, wh1, wl1, nullptr, nullptr, b1, gm1, bt1);
    mfmaconv_kernel<64, 128, false><<<dim3(16, 2, G), 512, 0, stream>>>(
        b64f, a128f, nullptr, wh2, wl2, nullptr, nullptr, b2, gm2, bt2);
    mfmaconv_kernel<128, 256, true><<<dim3(16, 4, G), 512, 0, stream>>>(
        a128f, nullptr, q4, wh3, wl3, w4h, w4l, b3, gm3, bt3);
    heads2_kernel<<<dim3(16, G), 256, 0, stream>>>(
        q4, b4, gm4, bt4, cw, cb, gw, gb, owp, obp,
        costb, out + 2 * 16 * HW, out + 3 * 16 * HW, g0);
  }

  astar_pass1_kernel<<<16, 64, 0, stream>>>(costb, startm, goalm, mapd, Jmeta, Jcells);
  astar_pass2_kernel<<<16, 64, 0, stream>>>(Jmeta, Jcells, goalm, out, out + 16 * HW);
}

// Round 15
// 389.793 us; speedup vs baseline: 1.3274x; 1.0040x over previous
//
#include <hip/hip_runtime.h>

#define HW 4096

typedef _Float16 f16;
typedef _Float16 f16x4 __attribute__((ext_vector_type(4)));
typedef _Float16 f16x8 __attribute__((ext_vector_type(8)));
typedef float    f32x4 __attribute__((ext_vector_type(4)));
typedef unsigned long long u64;

// ---------------------------------------------------------------------------
// fused prep: L1 weight transpose, MFMA weight repacks (w1..w3), w4 q-frag
// repack, and border-only zeroing of the padded f32 activation buffers.
// ---------------------------------------------------------------------------
__device__ inline void wrepack_one(const float* __restrict__ w,
                                   f16* __restrict__ wh, f16* __restrict__ wl,
                                   int cin, int idx)
{
  int j    = idx & 7;
  int lane = (idx >> 3) & 63;
  int mt   = (idx >> 9) & 3;
  int t    = idx >> 11;
  int tap  = t % 9;
  int t2   = t / 9;
  int chunks = cin >> 5;
  int chk  = t2 % chunks;
  int cg   = t2 / chunks;
  int co = cg * 64 + mt * 16 + (lane & 15);
  int k  = chk * 32 + 8 * (lane >> 4) + j;
  float v = w[((size_t)co * cin + k) * 9 + tap];
  f16 h = (f16)v;
  wh[idx] = h;
  wl[idx] = (f16)((v - (float)h) * 4096.0f);
}

__device__ inline void bzero_one(float* __restrict__ o, int C, int idx)
{
  int ch = idx % C;
  int rest = idx / C;
  int bp = rest % 260, bb = rest / 260;
  int r, c;
  if (bp < 66)       { r = 0;  c = bp; }
  else if (bp < 132) { r = 65; c = bp - 66; }
  else if (bp < 196) { c = 0;  r = bp - 132 + 1; }
  else               { c = 65; r = bp - 196 + 1; }
  o[(((size_t)bb * 66 + r) * 66 + c) * C + ch] = 0.f;
}

__global__ __launch_bounds__(256) void prep_kernel(
    const float* __restrict__ w0, float* __restrict__ wt0,
    const float* __restrict__ w1, f16* __restrict__ wh1, f16* __restrict__ wl1,
    const float* __restrict__ w2, f16* __restrict__ wh2, f16* __restrict__ wl2,
    const float* __restrict__ w3, f16* __restrict__ wh3, f16* __restrict__ wl3,
    const float* __restrict__ w4, f16* __restrict__ w4h, f16* __restrict__ w4l,
    float* __restrict__ a32f, float* __restrict__ b64f,
    float* __restrict__ a128f, int G)
{
  int idx = blockIdx.x * 256 + threadIdx.x;
  if (idx < 864) {                       // L1 wtrans: [(c*9+tap)][co]
    int co = idx % 32, rest = idx / 32;
    wt0[rest * 32 + co] = w0[co * 27 + rest];
    return;
  }
  idx -= 864;
  if (idx < 18432)  { wrepack_one(w1, wh1, wl1, 32, idx);  return; }
  idx -= 18432;
  if (idx < 73728)  { wrepack_one(w2, wh2, wl2, 64, idx);  return; }
  idx -= 73728;
  if (idx < 294912) { wrepack_one(w3, wh3, wl3, 128, idx); return; }
  idx -= 294912;
  if (idx < 4096) {                      // w4 q-frag repack
    int j = idx & 7, lane = (idx >> 3) & 63, cp = idx >> 9;
    int tap = lane & 15;
    int k = 8 * (lane >> 4) + j;
    int co = cp * 32 + k;
    float v = (tap < 9) ? w4[co * 9 + tap] : 0.f;
    f16 h = (f16)v;
    w4h[idx] = h;
    w4l[idx] = (f16)((v - (float)h) * 4096.0f);
    return;
  }
  idx -= 4096;
  int n32 = G * 260 * 32;
  if (idx < n32) { bzero_one(a32f, 32, idx); return; }
  idx -= n32;
  int n64 = G * 260 * 64;
  if (idx < n64) { bzero_one(b64f, 64, idx); return; }
  idx -= n64;
  int n128 = G * 260 * 128;
  if (idx < n128) { bzero_one(a128f, 128, idx); return; }
}

// ---------------------------------------------------------------------------
// L1: direct f32 3->32 conv + BN + ReLU -> padded NHWC f32 [66][66][32]
// ---------------------------------------------------------------------------
__global__ __launch_bounds__(128) void conv_l1_kernel(
    const float* __restrict__ mapd, const float* __restrict__ startm,
    const float* __restrict__ goalm,
    float* __restrict__ o32,         // [G][66][66][32]
    const float* __restrict__ wt,    // [(c*9+tap)][32]
    const float* __restrict__ bconv,
    const float* __restrict__ gamma, const float* __restrict__ beta,
    int b0)
{
  __shared__ float sIn[3][18][20];
  __shared__ float sW[3][9][32];
  const int tile = blockIdx.x;
  const int b    = blockIdx.z;
  const int gb   = b0 + b;
  const int y0 = (tile >> 2) << 4, x0 = (tile & 3) << 4;
  const int tid = threadIdx.x;
  const int cg = tid >> 6;
  const int pg = tid & 63;
  const int py = pg >> 2, px0 = (pg & 3) << 2;

  float acc[4][16];
  #pragma unroll
  for (int i = 0; i < 4; ++i)
    #pragma unroll
    for (int j = 0; j < 16; ++j) acc[i][j] = 0.f;

  for (int idx = tid; idx < 3 * 324; idx += 128) {
    int c = idx / 324, rem = idx - c * 324;
    int iy = rem / 18, ix = rem - iy * 18;
    int gy = y0 - 1 + iy, gx = x0 - 1 + ix;
    float v = 0.f;
    if ((unsigned)gy < 64u && (unsigned)gx < 64u) {
      const float* sp = (c == 0) ? mapd : ((c == 1) ? startm : goalm);
      v = sp[(gb << 12) + (gy << 6) + gx];
    }
    sIn[c][iy][ix] = v;
  }
  for (int idx = tid; idx < 3 * 9 * 32; idx += 128) {
    int co = idx % 32;
    int rest = idx / 32;
    sW[rest / 9][rest % 9][co] = wt[(size_t)rest * 32 + co];
  }
  __syncthreads();
  for (int c = 0; c < 3; ++c) {
    #pragma unroll
    for (int dy = 0; dy < 3; ++dy) {
      const float* rowp = &sIn[c][py + dy][px0];
      float4 ra = *(const float4*)rowp;
      float4 rb = *(const float4*)(rowp + 4);
      float r[6] = {ra.x, ra.y, ra.z, ra.w, rb.x, rb.y};
      #pragma unroll
      for (int dx = 0; dx < 3; ++dx) {
        const float4* wp = (const float4*)&sW[c][dy * 3 + dx][cg * 16];
        float4 w0 = wp[0], w1 = wp[1], w2 = wp[2], w3 = wp[3];
        float wv[16] = {w0.x, w0.y, w0.z, w0.w, w1.x, w1.y, w1.z, w1.w,
                        w2.x, w2.y, w2.z, w2.w, w3.x, w3.y, w3.z, w3.w};
        #pragma unroll
        for (int i = 0; i < 4; ++i)
          #pragma unroll
          for (int j = 0; j < 16; ++j)
            acc[i][j] = fmaf(r[dx + i], wv[j], acc[i][j]);
      }
    }
  }
  #pragma unroll
  for (int j = 0; j < 16; ++j) {
    int co = cg * 16 + j;
    float sc = gamma[co] / sqrtf(1.0f + 1e-5f);
    float bb = bconv[co], sh = beta[co];
    #pragma unroll
    for (int i = 0; i < 4; ++i) {
      float v = (acc[i][j] + bb) * sc + sh;
      v = fmaxf(v, 0.f);
      o32[(((size_t)b * 66 + (y0 + py + 1)) * 66 + (x0 + px0 + i + 1)) * 32 + co] = v;
    }
  }
}

// ---------------------------------------------------------------------------
// MFMA implicit-GEMM 3x3 conv, f16x3 split (exact to ~2^-22 rel/product).
// R15: k-major LDS layout sH/sL = [kg(4)][px(396)][8 f16].  B-frag reads are
// 16 consecutive 16B blocks per 16-lane group -> conflict-free ds_read_b128
// (old [px][32] layout had 64B row stride: lanes hit banks {0..3,16..19}
// only, ~4x serialization; SQ_LDS_BANK_CONFLICT 4.98M/dispatch).
// Numerics bit-identical to R12/R14.
// ---------------------------------------------------------------------------
template<int CIN, int COUT, bool QOUT>
__global__ __launch_bounds__(512, 4) void mfmaconv_kernel(
    const float* __restrict__ x,
    float* __restrict__ onhwc,
    float* __restrict__ qout,                 // [G][8][9][4096] when QOUT
    const f16* __restrict__ wh, const f16* __restrict__ wl,
    const f16* __restrict__ w4h, const f16* __restrict__ w4l,
    const float* __restrict__ bconv,
    const float* __restrict__ gamma, const float* __restrict__ beta)
{
  constexpr int CHUNKS = CIN / 32;
  __shared__ __align__(16) char smem[396 * 32 * 2 * 2];   // 50688 B
  f16* sH = (f16*)smem;                 // [4][396][8] k-major
  f16* sL = sH + 396 * 32;
  float (*sT)[36] = (float(*)[36])smem;                    // reused

  const int tid  = threadIdx.x;
  const int w    = tid >> 6, lane = tid & 63;
  const int l15  = lane & 15, lk = lane >> 4;
  const int rw   = w & 3, ch2 = w >> 2;
  const int tile = blockIdx.x;           // 0..15 (4 rows each)
  const int y0g  = tile << 2;
  const int cog  = blockIdx.y;
  const int cog0 = cog << 6;
  const int b    = blockIdx.z;

  f32x4 acc1[4][2], acc2[4][2];
  #pragma unroll
  for (int mt = 0; mt < 4; ++mt)
    #pragma unroll
    for (int n2 = 0; n2 < 2; ++n2) { acc1[mt][n2] = (f32x4)0.f; acc2[mt][n2] = (f32x4)0.f; }

  for (int chk = 0; chk < CHUNKS; ++chk) {
    __syncthreads();
    for (int idx = tid; idx < 3168; idx += 512) {
      int px = idx >> 3, c4 = idx & 7;
      int r = px / 66, c = px - r * 66;
      float4 v = *(const float4*)&x[(((size_t)b * 66 + y0g + r) * 66 + c) * CIN
                                    + chk * 32 + c4 * 4];
      float vv[4] = {v.x, v.y, v.z, v.w};
      f16x4 hv, lv;
      #pragma unroll
      for (int j = 0; j < 4; ++j) {
        f16 h = (f16)vv[j];
        hv[j] = h;
        lv[j] = (f16)((vv[j] - (float)h) * 4096.0f);
      }
      int kg = c4 >> 1, half = c4 & 1;
      *(f16x4*)&sH[(kg * 396 + px) * 8 + half * 4] = hv;
      *(f16x4*)&sL[(kg * 396 + px) * 8 + half * 4] = lv;
    }
    __syncthreads();
    #pragma unroll
    for (int tap = 0; tap < 9; ++tap) {
      const int dy = tap / 3, dx = tap - dy * 3;
      f16x8 Bh[2], Bl[2];
      #pragma unroll
      for (int n2 = 0; n2 < 2; ++n2) {
        int hp = (rw + dy) * 66 + (ch2 * 32 + n2 * 16 + l15 + dx);
        Bh[n2] = *(const f16x8*)&sH[(lk * 396 + hp) * 8];
        Bl[n2] = *(const f16x8*)&sL[(lk * 396 + hp) * 8];
      }
      #pragma unroll
      for (int mt = 0; mt < 4; ++mt) {
        size_t aoff = ((((size_t)(cog * CHUNKS + chk) * 9 + tap) * 4 + mt) * 64 + lane) * 8;
        f16x8 Ah = *(const f16x8*)&wh[aoff];
        f16x8 Al = *(const f16x8*)&wl[aoff];
        #pragma unroll
        for (int n2 = 0; n2 < 2; ++n2) {
          acc1[mt][n2] = __builtin_amdgcn_mfma_f32_16x16x32_f16(Ah, Bh[n2], acc1[mt][n2], 0, 0, 0);
          acc2[mt][n2] = __builtin_amdgcn_mfma_f32_16x16x32_f16(Ah, Bl[n2], acc2[mt][n2], 0, 0, 0);
          acc2[mt][n2] = __builtin_amdgcn_mfma_f32_16x16x32_f16(Al, Bh[n2], acc2[mt][n2], 0, 0, 0);
        }
      }
    }
  }

  // epilogue: two 32-cout passes via LDS transpose
  #pragma unroll
  for (int p = 0; p < 2; ++p) {
    __syncthreads();
    #pragma unroll
    for (int m1 = 0; m1 < 2; ++m1) {
      const int mt = 2 * p + m1;
      #pragma unroll
      for (int n2 = 0; n2 < 2; ++n2)
        #pragma unroll
        for (int i = 0; i < 4; ++i) {
          int co = cog0 + p * 32 + m1 * 16 + 4 * lk + i;
          float v = acc1[mt][n2][i] + acc2[mt][n2][i] * (1.0f / 4096.0f);
          float sc = gamma[co] / sqrtf(1.0f + 1e-5f);
          v = (v + bconv[co]) * sc + beta[co];
          v = fmaxf(v, 0.f);
          sT[rw * 64 + ch2 * 32 + n2 * 16 + l15][m1 * 16 + 4 * lk + i] = v;
        }
    }
    __syncthreads();
    if constexpr (QOUT) {
      const int cp = cog * 2 + p;
      f16x8 A_h = *(const f16x8*)&w4h[(cp * 64 + lane) * 8];
      f16x8 A_l = *(const f16x8*)&w4l[(cp * 64 + lane) * 8];
      #pragma unroll
      for (int nt2 = 0; nt2 < 2; ++nt2) {
        int nt = w * 2 + nt2;
        const float* bp = &sT[nt * 16 + l15][8 * lk];
        float4 v0 = *(const float4*)bp;
        float4 v1 = *(const float4*)(bp + 4);
        float bvv[8] = {v0.x, v0.y, v0.z, v0.w, v1.x, v1.y, v1.z, v1.w};
        f16x8 Bh, Bl;
        #pragma unroll
        for (int j = 0; j < 8; ++j) {
          f16 h = (f16)bvv[j];
          Bh[j] = h;
          Bl[j] = (f16)((bvv[j] - (float)h) * 4096.0f);
        }
        f32x4 q1 = (f32x4)0.f, q2 = (f32x4)0.f;
        q1 = __builtin_amdgcn_mfma_f32_16x16x32_f16(A_h, Bh, q1, 0, 0, 0);
        q2 = __builtin_amdgcn_mfma_f32_16x16x32_f16(A_h, Bl, q2, 0, 0, 0);
        q2 = __builtin_amdgcn_mfma_f32_16x16x32_f16(A_l, Bh, q2, 0, 0, 0);
        #pragma unroll
        for (int i = 0; i < 4; ++i) {
          int tap = 4 * lk + i;
          if (tap < 9)
            qout[(((size_t)b * 8 + cp) * 9 + tap) * HW + tile * 256 + nt * 16 + l15]
                = q1[i] + q2[i] * (1.0f / 4096.0f);
        }
      }
    } else {
      int px = tid >> 1, half = tid & 1;
      int row = px >> 6, col = px & 63;
      size_t base = (((size_t)b * 66 + y0g + row + 1) * 66 + col + 1) * COUT
                    + cog0 + p * 32 + half * 16;
      #pragma unroll
      for (int jj = 0; jj < 4; ++jj) {
        float4 o;
        o.x = sT[px][half * 16 + jj * 4 + 0];
        o.y = sT[px][half * 16 + jj * 4 + 1];
        o.z = sT[px][half * 16 + jj * 4 + 2];
        o.w = sT[px][half * 16 + jj * 4 + 3];
        *(float4*)&onhwc[base + jj * 4] = o;
      }
    }
  }
}

// ---------------------------------------------------------------------------
// heads finish (unchanged)
// ---------------------------------------------------------------------------
__global__ __launch_bounds__(256) void heads2_kernel(
    const float* __restrict__ q4,       // [G][8][9][4096]
    const float* __restrict__ b4, const float* __restrict__ gm4,
    const float* __restrict__ bt4,
    const float* __restrict__ cw, const float* __restrict__ cb,
    const float* __restrict__ gw, const float* __restrict__ gb,
    const float* __restrict__ ow, const float* __restrict__ ob,
    float* __restrict__ costout,
    float* __restrict__ geoout, float* __restrict__ obsout,
    int b0)
{
  const int bl = blockIdx.y;
  const int px = blockIdx.x * 256 + threadIdx.x;
  const int y = px >> 6, x = px & 63;
  float s = 0.f;
  for (int cp = 0; cp < 8; ++cp) {
    const float* qb = &q4[((size_t)bl * 8 + cp) * 9 * HW];
    #pragma unroll
    for (int tap = 0; tap < 9; ++tap) {
      int yy = y + tap / 3 - 1, xx = x + tap % 3 - 1;
      if ((unsigned)yy < 64u && (unsigned)xx < 64u)
        s += qb[tap * HW + (yy << 6) + xx];
    }
  }
  float sc = gm4[0] / sqrtf(1.0f + 1e-5f);
  float f  = (s + b4[0]) * sc + bt4[0];
  float cv = 1.f / (1.f + expf(-(f * cw[0] + cb[0])));
  float gv = fmaxf(f * gw[0] + gb[0], 0.f);
  float ov = fmaxf(f * ow[0] + ob[0], 0.f);
  int gbi = b0 + bl;
  costout[gbi * HW + px] = cv;
  geoout[gbi * HW + px]  = gv;
  obsout[gbi * HW + px]  = ov;
}

// ---------------------------------------------------------------------------
// A* pass 1 (unchanged -- u64 packed keys + exp factoring)
// ---------------------------------------------------------------------------
__device__ inline u64 pkey(float fe, int idx) {
  return ((u64)__float_as_uint(fe) << 32) | (unsigned)(~idx);
}

__global__ __launch_bounds__(64) void astar_pass1_kernel(
    const float* __restrict__ costm,
    const float* __restrict__ startm,
    const float* __restrict__ goalm,
    const float* __restrict__ mapd,
    unsigned short* __restrict__ Jmeta,
    unsigned short* __restrict__ Jcells)
{
  __shared__ float4 cell[HW];   // g, flag, Eh(=exp(-h/16)), cost
  __shared__ float2 pk[HW];     // fe, gc(=g+cost)
  const int b = blockIdx.x, lane = threadIdx.x;

  int gi = 0x7fffffff;
  for (int i = lane; i < HW; i += 64)
    if (goalm[b * HW + i] > 0.5f) gi = min(gi, i);
  #pragma unroll
  for (int m = 32; m; m >>= 1) gi = min(gi, __shfl_xor(gi, m));
  const int goal_idx = gi;
  const float gyf = (float)(goal_idx >> 6), gxf = (float)(goal_idx & 63);

  for (int i = lane; i < HW; i += 64) {
    float c_ = costm[b * HW + i];
    float iy = (float)(i >> 6), ix = (float)(i & 63);
    float d0 = fabsf(iy - gyf), d1 = fabsf(ix - gxf);
    float cheb = (d0 + d1) - fminf(d0, d1);
    float euc  = sqrtf(d0 * d0 + d1 * d1);
    float h = (cheb + 0.001f * euc) + c_;
    float Eh = expf(-((0.5f * h) * 0.125f));   // exp(-h/16)
    bool st = startm[b * HW + i] > 0.5f;
    float flg = st ? 1.f : ((mapd[b * HW + i] > 0.5f) ? 0.f : 2.f);
    cell[i] = make_float4(0.f, flg, Eh, c_);
    pk[i] = make_float2(st ? Eh : 0.f, c_);
  }
  __syncthreads();

  u64 gmk = 0ull; float ggc = 0.f;
  {
    int base = lane << 6;
    for (int k = 0; k < 64; ++k) {
      int ci = base + ((k + lane) & 63);
      float2 p = pk[ci];
      u64 kk = pkey(p.x, ci);
      if (kk > gmk) { gmk = kk; ggc = p.y; }
    }
  }

  u64 K = gmk; float gc = ggc;
  #pragma unroll
  for (int m = 32; m; m >>= 1) {
    u64 ko = __shfl_xor(K, m);
    float co = __shfl_xor(gc, m);
    if (ko > K) { K = ko; gc = co; }
  }

  int t = 0;
  for (; t < 512; ++t) {
    const int ind = (int)(~(unsigned)K) & (HW - 1);
    const float g2 = gc;
    const bool unsolved = (ind != goal_idx);
    const int r = ind >> 6, cx = ind & 63;
    const float eg = expf(-g2 * 0.0625f);    // wave-uniform, off-chain

    const int rb = (r << 6) + lane;
    float2 rp = pk[rb];

    int pcell = -1; float pval = 0.f, pgc = 0.f;
    if (lane < 8) {
      int kk = (lane >= 4) ? lane + 1 : lane;
      int ny = r + (kk / 3) - 1, nx = cx + (kk % 3) - 1;
      if ((unsigned)ny < 64u && (unsigned)nx < 64u) {
        int n = (ny << 6) + nx;
        float4 cd = cell[n];
        bool trig = (cd.y == 1.f) ? (cd.x > g2) : (cd.y == 0.f);
        if (trig) {
          float fv = eg * cd.z;
          *(float2*)&cell[n] = make_float2(g2, 1.f);
          pk[n] = make_float2(fv, g2 + cd.w);
          pcell = n; pval = fv; pgc = g2 + cd.w;
        }
      }
      Jcells[((size_t)b * 512 + t) * 8 + lane] =
          (unsigned short)(pcell >= 0 ? pcell : 0xFFFF);
    } else if (lane == 8) {
      if (unsolved) {
        cell[ind].y = 2.f;
        pk[ind].x  = 0.f;
      }
      Jmeta[b * 512 + t] = (unsigned short)(ind | (unsolved ? 0 : 0x8000));
    }

    u64 kB = (unsolved && lane == cx) ? 0ull : pkey(rp.x, rb);
    float bgc = rp.y;

    const bool fixpoint = (!unsolved) && !__any(pcell >= 0);
    if (fixpoint) { ++t; break; }

    #pragma unroll
    for (int k = 0; k < 8; ++k) {
      int   pc = __shfl(pcell, k);
      float pv = __shfl(pval, k);
      float pg = __shfl(pgc, k);
      if (pc >= 0) {
        u64 kk = pkey(pv, pc);
        if ((pc >> 6) == r && (pc & 63) == lane) {
          if (kk > kB) { kB = kk; bgc = pg; }
        }
        if ((pc >> 6) == lane) {
          if (kk > gmk) { gmk = kk; ggc = pg; }
        }
      }
    }

    u64 kC; float cgc;
    if (unsolved && lane == r) { kC = kB; cgc = bgc; }
    else if (gmk > kB)         { kC = gmk; cgc = ggc; }
    else                       { kC = kB;  cgc = bgc; }

    #pragma unroll
    for (int m = 32; m; m >>= 1) {
      u64   ko  = __shfl_xor(kC, m);
      float co  = __shfl_xor(cgc, m);
      u64   kbo = __shfl_xor(kB, m);
      float bgo = __shfl_xor(bgc, m);
      if (ko  > kC) { kC = ko;  cgc = co;  }
      if (kbo > kB) { kB = kbo; bgc = bgo; }
    }
    if (unsolved && lane == r) { gmk = kB; ggc = bgc; }
    K = kC; gc = cgc;
  }

  {
    unsigned short jm = (unsigned short)(goal_idx | 0x8000);
    uint4* jc4 = (uint4*)Jcells;
    for (int tt = t + lane; tt < 512; tt += 64) {
      Jmeta[b * 512 + tt] = jm;
      jc4[(size_t)b * 512 + tt] =
          make_uint4(0xFFFFFFFFu, 0xFFFFFFFFu, 0xFFFFFFFFu, 0xFFFFFFFFu);
    }
  }
}

// ---------------------------------------------------------------------------
// A* pass 2 (unchanged)
// ---------------------------------------------------------------------------
__global__ __launch_bounds__(64) void astar_pass2_kernel(
    const unsigned short* __restrict__ Jmeta,
    const unsigned short* __restrict__ Jcells,
    const float* __restrict__ goalm,
    float* __restrict__ out_hist, float* __restrict__ out_path)
{
  __shared__ unsigned short par[HW];
  __shared__ unsigned short jm[64];
  __shared__ unsigned short jc[64][8];
  const int b = blockIdx.x, lane = threadIdx.x;

  for (int i = lane; i < HW; i += 64) {
    out_hist[b * HW + i] = 0.f;
    out_path[b * HW + i] = 0.f;
  }
  int localmin = 512;
  for (int t = lane; t < 512; t += 64) {
    bool all16 = true;
    for (int bb = 0; bb < 16; ++bb)
      all16 = all16 && ((Jmeta[bb * 512 + t] & 0x8000u) != 0);
    if (all16) localmin = min(localmin, t);
  }
  #pragma unroll
  for (int m = 32; m; m >>= 1) localmin = min(localmin, __shfl_xor(localmin, m));
  const int t_last = (localmin < 512) ? localmin : 511;

  int gi = 0x7fffffff;
  for (int i = lane; i < HW; i += 64)
    if (goalm[b * HW + i] > 0.5f) gi = min(gi, i);
  #pragma unroll
  for (int m = 32; m; m >>= 1) gi = min(gi, __shfl_xor(gi, m));

  for (int i = lane; i < HW; i += 64) par[i] = (unsigned short)gi;
  __syncthreads();

  for (int t0 = 0; t0 <= t_last; t0 += 64) {
    if (t0 + lane < 512) {
      jm[lane] = Jmeta[b * 512 + t0 + lane];
      const unsigned short* src = &Jcells[((size_t)b * 512 + t0 + lane) * 8];
      #pragma unroll
      for (int k = 0; k < 8; ++k) jc[lane][k] = src[k];
    }
    __syncthreads();
    int te = min(t_last - t0, 63);
    for (int tt = 0; tt <= te; ++tt) {
      int ind = jm[tt] & 0x0FFF;
      if (lane < 8) {
        unsigned short c = jc[tt][lane];
        if (c != 0xFFFFu) par[c] = (unsigned short)ind;
      } else if (lane == 8) {
        out_hist[b * HW + ind] = 1.0f;
      }
    }
    __syncthreads();
  }
  if (lane == 0) {
    out_path[b * HW + gi] = 1.0f;
    int loc = par[gi];
    for (int i = 0; i < t_last; ++i) {
      out_path[b * HW + loc] = 1.0f;
      loc = par[loc];
    }
  }
}

// ---------------------------------------------------------------------------
extern "C" void kernel_launch(void* const* d_in, const int* in_sizes, int n_in,
                              void* d_out, int out_size, void* d_ws, size_t ws_size,
                              hipStream_t stream)
{
  (void)in_sizes; (void)n_in; (void)out_size;
  const float* mapd   = (const float*)d_in[0];
  const float* startm = (const float*)d_in[1];
  const float* goalm  = (const float*)d_in[2];
  const float* w0 = (const float*)d_in[3];
  const float* b0 = (const float*)d_in[4];
  const float* gm0= (const float*)d_in[5];
  const float* bt0= (const float*)d_in[6];
  const float* w1 = (const float*)d_in[7];
  const float* b1 = (const float*)d_in[8];
  const float* gm1= (const float*)d_in[9];
  const float* bt1= (const float*)d_in[10];
  const float* w2 = (const float*)d_in[11];
  const float* b2 = (const float*)d_in[12];
  const float* gm2= (const float*)d_in[13];
  const float* bt2= (const float*)d_in[14];
  const float* w3 = (const float*)d_in[15];
  const float* b3 = (const float*)d_in[16];
  const float* gm3= (const float*)d_in[17];
  const float* bt3= (const float*)d_in[18];
  const float* w4 = (const float*)d_in[19];
  const float* b4 = (const float*)d_in[20];
  const float* gm4= (const float*)d_in[21];
  const float* bt4= (const float*)d_in[22];
  const float* cw = (const float*)d_in[23];
  const float* cb = (const float*)d_in[24];
  const float* gw = (const float*)d_in[25];
  const float* gb = (const float*)d_in[26];
  const float* owp= (const float*)d_in[27];
  const float* obp= (const float*)d_in[28];
  float* out = (float*)d_out;

  char* wsb = (char*)d_ws;
  size_t off = 0;
  auto alloc = [&](size_t bytes) {
    void* p = wsb + off;
    off = (off + bytes + 255) & ~(size_t)255;
    return p;
  };
  float* wt0 = (float*)alloc(864 * 4);
  f16* wh1 = (f16*)alloc(64  * 9 * 32  * 2);
  f16* wl1 = (f16*)alloc(64  * 9 * 32  * 2);
  f16* wh2 = (f16*)alloc(128 * 9 * 64  * 2);
  f16* wl2 = (f16*)alloc(128 * 9 * 64  * 2);
  f16* wh3 = (f16*)alloc(256 * 9 * 128 * 2);
  f16* wl3 = (f16*)alloc(256 * 9 * 128 * 2);
  f16* w4h = (f16*)alloc(4096 * 2);
  f16* w4l = (f16*)alloc(4096 * 2);
  float* costb = (float*)alloc(16 * HW * 4);
  unsigned short* Jmeta  = (unsigned short*)alloc(16 * 512 * 2);
  unsigned short* Jcells = (unsigned short*)alloc(16 * 512 * 8 * 2);
  size_t fixed = off;

  const size_t A32  = 66 * 66 * 32  * 4;
  const size_t B64  = 66 * 66 * 64  * 4;
  const size_t A128 = 66 * 66 * 128 * 4;
  const size_t Q4   = 8 * 9 * HW * 4;
  const size_t perG = A32 + B64 + A128 + Q4 + 4 * 256;

  int G = 16;
  while (G > 1 && fixed + (size_t)G * perG > ws_size) G >>= 1;

  float* a32f  = (float*)alloc(G * A32);
  float* b64f  = (float*)alloc(G * B64);
  float* a128f = (float*)alloc(G * A128);
  float* q4    = (float*)alloc(G * Q4);

  int prep_total = 864 + 18432 + 73728 + 294912 + 4096 + G * 260 * (32 + 64 + 128);
  prep_kernel<<<(prep_total + 255) / 256, 256, 0, stream>>>(
      w0, wt0, w1, wh1, wl1, w2, wh2, wl2, w3, wh3, wl3, w4, w4h, w4l,
      a32f, b64f, a128f, G);

  for (int g0 = 0; g0 < 16; g0 += G) {
    conv_l1_kernel<<<dim3(16, 1, G), 128, 0, stream>>>(
        mapd, startm, goalm, a32f, wt0, b0, gm0, bt0, g0);
    mfmaconv_kernel<32, 64, false><<<dim3(16, 1, G), 512, 0, stream>>>(
        a32f, b64f, nullptr, wh1, wl1, nullptr, nullptr, b1, gm1, bt1);
    mfmaconv_kernel<64, 128, false><<<dim3(16, 2, G), 512, 0, stream>>>(
        b64f, a128f, nullptr, wh2, wl2, nullptr, nullptr, b2, gm2, bt2);
    mfmaconv_kernel<128, 256, true><<<dim3(16, 4, G), 512, 0, stream>>>(
        a128f, nullptr, q4, wh3, wl3, w4h, w4l, b3, gm3, bt3);
    heads2_kernel<<<dim3(16, G), 256, 0, stream>>>(
        q4, b4, gm4, bt4, cw, cb, gw, gb, owp, obp,
        costb, out + 2 * 16 * HW, out + 3 * 16 * HW, g0);
  }

  astar_pass1_kernel<<<16, 64, 0, stream>>>(costb, startm, goalm, mapd, Jmeta, Jcells);
  astar_pass2_kernel<<<16, 64, 0, stream>>>(Jmeta, Jcells, goalm, out, out + 16 * HW);
}